// Round 19
// baseline (203.944 us; speedup 1.0000x reference)
//
#include <hip/hip_runtime.h>

#define NN 50000
#define EE 800000
#define KC 64          // histogram copies (one hist block each)
#define EPC (EE / KC)  // 12500 edges per hist block
#define DEG_SCALE 4096.0f
#define NPANEL 782

typedef float f32x4 __attribute__((ext_vector_type(4)));
typedef short bf16x8 __attribute__((ext_vector_type(8)));
typedef unsigned short u16x8 __attribute__((ext_vector_type(8)));

__device__ __forceinline__ unsigned short f2bf(float f) {
  unsigned int u = __float_as_uint(f);
  u += 0x7fffu + ((u >> 16) & 1u);
  return (unsigned short)(u >> 16);
}
__device__ __forceinline__ float bf2f(unsigned short u) {
  return __uint_as_float(((unsigned int)u) << 16);
}

// ---- fp8 e4m3 (bit-matched manual encode/decode; OCP-style, bias 7) ----
__device__ __forceinline__ unsigned f2fp8(float f) {
  const unsigned u = __float_as_uint(f);
  const unsigned s = (u >> 24) & 0x80u;
  unsigned mag = u & 0x7fffffffu;
  if (mag >= 0x43E00000u) return s | 0x7Eu;   // clamp to 448
  if (mag < 0x3C800000u) {                    // < 2^-6: subnormal, step 2^-9
    const int m = (int)(__uint_as_float(mag) * 512.0f + 0.5f);
    return s | (unsigned)m;                   // m in [0,8]; 8 == 2^-6 normal
  }
  const unsigned lsb = (mag >> 20) & 1u;
  mag += 0x0007FFFFu + lsb;                   // RNE to 3 mantissa bits
  return s | (((mag >> 23) - 120u) << 3) | ((mag >> 20) & 7u);
}
__device__ __forceinline__ float fp82f(unsigned b) {
  const unsigned s = (b & 0x80u) << 24;
  const unsigned em = b & 0x7fu;
  const float sub = (float)em * 0.001953125f;  // m * 2^-9
  return (em < 8u) ? __uint_as_float(s | __float_as_uint(sub))
                   : __uint_as_float(s | ((em << 20) + 0x3C000000u));
}

__device__ __forceinline__ void async_copy16(const void* g, void* l) {
  __builtin_amdgcn_global_load_lds(
      (const __attribute__((address_space(1))) unsigned int*)g,
      (__attribute__((address_space(3))) unsigned int*)l, 16, 0, 0);
}

__device__ __forceinline__ float fast_sig(float x) {
  return __builtin_amdgcn_rcpf(1.f + __expf(-x));
}
__device__ __forceinline__ float fast_tanh(float x) {
  return 1.f - 2.f * __builtin_amdgcn_rcpf(__expf(2.f * x) + 1.f);
}

// ---- u16-slot scratch in the first 256B of each 512B d_out row ----
__device__ __forceinline__ unsigned short* hslot2(char* o, long j) {
  return (unsigned short*)(o + (j >> 7) * 512 + (j & 127) * 2);
}
// h-region slots: deg copies [0, 3.2M) ; cnt copies [3.2M, 6.4M)
// c-region slots: segbase [0, 3.2M) ; rank [3.2M, 4.0M)
#define CNT_SLOT0 3200000L
#define RANK_SLOT0 3200000L

// ---------------- phase 1: single-pass LDS histograms + buildB + h/x->bf16 (+h->fp8) ----------------
// buildB theta-fold: out = x*W + h*(th0-th2) + M1*th1 + M2*(2*th2), M2 = L*M1
__global__ __launch_bounds__(1024) void k_pre(
    const float* __restrict__ Wi, const float* __restrict__ Wf,
    const float* __restrict__ Wc, const float* __restrict__ Wo,
    const float* __restrict__ Ti, const float* __restrict__ Tf,
    const float* __restrict__ Tc, const float* __restrict__ To,
    unsigned short* __restrict__ bglob, const float* __restrict__ h,
    const float* __restrict__ x, char* __restrict__ outB,
    const int* __restrict__ src, const int* __restrict__ dst,
    const float* __restrict__ w, unsigned char* __restrict__ h8) {
  const int b = blockIdx.x, tid = threadIdx.x;
  char* cB = outB + (long)NN * 512;
  if (b < KC) {
    __shared__ unsigned histC[12500];  //  50 KB: cnt, packed 4 x u8
    __shared__ unsigned histD[25000];  // 100 KB: deg, packed 2 x u16 fixed-point
    const int base = b * EPC;
    for (int j = tid; j < 12500; j += 1024) histC[j] = 0u;
    for (int j = tid; j < 25000; j += 1024) histD[j] = 0u;
    __syncthreads();
    for (int k = tid; k < EPC; k += 1024) {
      const int e = base + k;
      const int d = dst[e], s = src[e];
      const float wv = w[e];
      const int shc = (d & 3) * 8;
      const unsigned old = atomicAdd(&histC[d >> 2], 1u << shc);
      *hslot2(cB, RANK_SLOT0 + e) = (unsigned short)((old >> shc) & 0xffu);
      const unsigned q = (unsigned)__float2uint_rn(wv * DEG_SCALE);
      atomicAdd(&histD[s >> 1], q << ((s & 1) * 16));
    }
    __syncthreads();
    for (int j = tid; j < 12500; j += 1024) {
      const unsigned v = histC[j];
      const unsigned lo = (v & 0xffu) | (((v >> 8) & 0xffu) << 16);
      const unsigned hi = ((v >> 16) & 0xffu) | (((v >> 24) & 0xffu) << 16);
      uint2 pk; pk.x = lo; pk.y = hi;
      *(uint2*)hslot2(outB, CNT_SLOT0 + (long)b * NN + 4L * j) = pk;
    }
    for (int j = tid; j < 25000; j += 1024)
      *(unsigned*)hslot2(outB, (long)b * NN + 2L * j) = histD[j];
  } else if (b < KC + 32) {
    // buildB: fragment-native, theta-folded
    const int t = (b - KC) * 1024 + tid;  // 0..32767
    const int ks = t >> 11;
    const int cf = (t >> 6) & 31;
    const int lane = t & 63;
    const int wv = cf >> 3, hl = (cf >> 2) & 1, g = cf & 3;
    const int kg = lane >> 4, lm = lane & 15;
    const int hc = (wv * 2 + hl) * 16 + lm;
    const float* Wg = (g == 0) ? Wi : (g == 1) ? Wf : (g == 2) ? Wc : Wo;
    const float* Tg = (g == 0) ? Ti : (g == 1) ? Tf : (g == 2) ? Tc : To;
    u16x8 out;
#pragma unroll
    for (int dk = 0; dk < 8; ++dk) {
      const int k = ks * 32 + kg * 8 + dk;
      const int kb = k >> 7, r = k & 127;
      float v;
      if (kb == 0)      v = Wg[r * 128 + hc];
      else if (kb == 1) v = Tg[r * 128 + hc] - Tg[2 * 16384 + r * 128 + hc];
      else if (kb == 2) v = Tg[16384 + r * 128 + hc];
      else              v = 2.f * Tg[2 * 16384 + r * 128 + hc];
      out[dk] = f2bf(v);
    }
    *(u16x8*)(bglob + t * 8) = out;
  } else if (b < KC + 32 + 782) {
    const int i = (b - (KC + 32)) * 1024 + tid;  // 8-f32 chunks of h
    if (i < 100000 * 8) {
      const float* hp = h + i * 8;
      const f32x4 v0 = *(const f32x4*)hp;
      const f32x4 v1 = *(const f32x4*)(hp + 4);
      u16x8 o;
#pragma unroll
      for (int e = 0; e < 4; ++e) o[e] = f2bf(v0[e]);
#pragma unroll
      for (int e = 0; e < 4; ++e) o[e + 4] = f2bf(v1[e]);
      *(u16x8*)(outB + (i >> 4) * 512 + 256 + (i & 15) * 16) = o;
      // fp8 copy for gather1 reads
      unsigned lo8 = 0, hi8 = 0;
#pragma unroll
      for (int e = 0; e < 4; ++e) lo8 |= f2fp8(v0[e]) << (8 * e);
#pragma unroll
      for (int e = 0; e < 4; ++e) hi8 |= f2fp8(v1[e]) << (8 * e);
      uint2 pk; pk.x = lo8; pk.y = hi8;
      *(uint2*)(h8 + (long)i * 8) = pk;
    }
  } else {
    const int i = (b - (KC + 32 + 782)) * 1024 + tid;
    if (i < 100000 * 8) {
      const float* xp = x + i * 8;
      const f32x4 v0 = *(const f32x4*)xp;
      const f32x4 v1 = *(const f32x4*)(xp + 4);
      u16x8 o;
#pragma unroll
      for (int e = 0; e < 4; ++e) o[e] = f2bf(v0[e]);
#pragma unroll
      for (int e = 0; e < 4; ++e) o[e + 4] = f2bf(v1[e]);
      *(u16x8*)(cB + (i >> 4) * 512 + 256 + (i & 15) * 16) = o;
    }
  }
}

// ---------------- phase 2: wave-per-node copy reduction/scan ----------------
__global__ __launch_bounds__(256) void k_phase2(char* __restrict__ outB,
                                                float* __restrict__ dinv,
                                                int* __restrict__ wscnt) {
  char* cB = outB + (long)NN * 512;
  const int lane = threadIdx.x & 63;  // copy index c
  const int i = blockIdx.x * 4 + (threadIdx.x >> 6);
  const int c = lane;
  const int cnt_c = (int)*hslot2(outB, CNT_SLOT0 + (long)c * NN + i);
  const float deg_c = (float)*hslot2(outB, (long)c * NN + i);
  int x = cnt_c;
#pragma unroll
  for (int d = 1; d < 64; d <<= 1) {
    const int y = __shfl_up(x, d, 64);
    if (lane >= d) x += y;
  }
  *hslot2(cB, (long)c * NN + i) = (unsigned short)(x - cnt_c);
  float s = deg_c;
#pragma unroll
  for (int d = 1; d < 64; d <<= 1) s += __shfl_xor(s, d, 64);
  if (lane == 0) {
    s *= (1.0f / DEG_SCALE);
    dinv[i] = (s > 0.f) ? rsqrtf(fmaxf(s, 1e-30f)) : 0.f;
  }
  if (lane == 63) wscnt[i] = x;  // inclusive node total
}

// ---------------- scan machinery ----------------
__device__ __forceinline__ int block_scan_excl_256(int v, int* total) {
  __shared__ int wsum[4];
  const int tid = threadIdx.x;
  const int lane = tid & 63, wv = tid >> 6;
  int x = v;
#pragma unroll
  for (int d = 1; d < 64; d <<= 1) {
    const int y = __shfl_up(x, d, 64);
    if (lane >= d) x += y;
  }
  if (lane == 63) wsum[wv] = x;
  __syncthreads();
  int pre = 0, tot = 0;
#pragma unroll
  for (int u = 0; u < 4; ++u) {
    const int s = wsum[u];
    pre += (u < wv) ? s : 0;
    tot += s;
  }
  *total = tot;
  return pre + x - v;
}

__global__ void k_scan1(const int* __restrict__ wscnt, int* __restrict__ bsum) {
  const int i = blockIdx.x * 256 + threadIdx.x;
  const int v = (i < NN) ? wscnt[i] : 0;
  int tot;
  block_scan_excl_256(v, &tot);
  if (threadIdx.x == 0) bsum[blockIdx.x] = tot;
}

// scan3 with self-computed block prefix
__global__ void k_scan3(const int* __restrict__ wscnt, const int* __restrict__ bsum,
                        int* __restrict__ off) {
  const int tid = threadIdx.x;
  const int vb = (tid < 196 && tid < (int)blockIdx.x) ? bsum[tid] : 0;
  int pre;
  block_scan_excl_256(vb, &pre);
  __syncthreads();
  const int i = blockIdx.x * 256 + tid;
  const int v = (i < NN) ? wscnt[i] : 0;
  int tot;
  const int excl = block_scan_excl_256(v, &tot) + pre;
  if (i < NN) off[i] = excl;
  if (i == NN) off[NN] = excl;
}

// atomic-free CSR fill: p = off[d] + segbase[copy][d] + rank[e]
// record: low16 = src (u16), high16 = wn (bf16)
__global__ void k_edge2(const int* __restrict__ src, const int* __restrict__ dst,
                        const float* __restrict__ w, const float* __restrict__ dinv,
                        const int* __restrict__ off, char* __restrict__ outB,
                        unsigned* __restrict__ ed) {
  const int e = blockIdx.x * blockDim.x + threadIdx.x;
  if (e >= EE) return;
  char* cB = outB + (long)NN * 512;
  const int s = src[e], d = dst[e];
  const int c = e / EPC;
  const int p = off[d] + (int)*hslot2(cB, (long)c * NN + d) +
                (int)*hslot2(cB, RANK_SLOT0 + e);
  const float wn = -w[e] * dinv[s] * dinv[d];
  ed[p] = (unsigned)s | ((unsigned)f2bf(wn) << 16);
}

// ---------------- sparse gather (fp8 src rows, 1 wave per node) ----------------
// reads vin8[src*128 + lane*2] (2 fp8/lane); writes bf16 pair to voutB row and,
// if vout8 != null, an fp8 pair to vout8 (consumed by the next gather).
__global__ __launch_bounds__(256) void k_gather(
    const unsigned char* __restrict__ vin8, const int* __restrict__ off,
    const unsigned* __restrict__ ed, char* __restrict__ voutB,
    unsigned char* __restrict__ vout8) {
  const int wid = threadIdx.x >> 6, lane = threadIdx.x & 63;
  const int node = blockIdx.x * 4 + wid;
  const int p0 = off[node], p1 = off[node + 1];
  const int lb2 = lane * 2;
  float ax0 = 0.f, ay0 = 0.f, ax1 = 0.f, ay1 = 0.f;
  float ax2 = 0.f, ay2 = 0.f, ax3 = 0.f, ay3 = 0.f;
  int p = p0;
  for (; p + 7 < p1; p += 8) {
    unsigned E[8];
    unsigned short V[8];
#pragma unroll
    for (int u = 0; u < 8; ++u) E[u] = ed[p + u];
#pragma unroll
    for (int u = 0; u < 8; ++u)
      V[u] = *(const unsigned short*)(vin8 + (long)(E[u] & 0xffffu) * 128 + lb2);
#pragma unroll
    for (int u = 0; u < 8; ++u) {
      const float wv = bf2f((unsigned short)(E[u] >> 16));
      float* ax = (u & 3) == 0 ? &ax0 : (u & 3) == 1 ? &ax1 : (u & 3) == 2 ? &ax2 : &ax3;
      float* ay = (u & 3) == 0 ? &ay0 : (u & 3) == 1 ? &ay1 : (u & 3) == 2 ? &ay2 : &ay3;
      *ax = fmaf(wv, fp82f(V[u] & 0xffu), *ax);
      *ay = fmaf(wv, fp82f(V[u] >> 8), *ay);
    }
  }
  for (; p + 3 < p1; p += 4) {
    unsigned E[4];
    unsigned short V[4];
#pragma unroll
    for (int u = 0; u < 4; ++u) E[u] = ed[p + u];
#pragma unroll
    for (int u = 0; u < 4; ++u)
      V[u] = *(const unsigned short*)(vin8 + (long)(E[u] & 0xffffu) * 128 + lb2);
#pragma unroll
    for (int u = 0; u < 4; ++u) {
      const float wv = bf2f((unsigned short)(E[u] >> 16));
      float* ax = (u & 3) == 0 ? &ax0 : (u & 3) == 1 ? &ax1 : (u & 3) == 2 ? &ax2 : &ax3;
      float* ay = (u & 3) == 0 ? &ay0 : (u & 3) == 1 ? &ay1 : (u & 3) == 2 ? &ay2 : &ay3;
      *ax = fmaf(wv, fp82f(V[u] & 0xffu), *ax);
      *ay = fmaf(wv, fp82f(V[u] >> 8), *ay);
    }
  }
  for (; p < p1; ++p) {
    const unsigned e0 = ed[p];
    const unsigned short v0 =
        *(const unsigned short*)(vin8 + (long)(e0 & 0xffffu) * 128 + lb2);
    const float w0 = bf2f((unsigned short)(e0 >> 16));
    ax0 = fmaf(w0, fp82f(v0 & 0xffu), ax0);
    ay0 = fmaf(w0, fp82f(v0 >> 8), ay0);
  }
  const float rx = (ax0 + ax1) + (ax2 + ax3);
  const float ry = (ay0 + ay1) + (ay2 + ay3);
  const unsigned ow = (unsigned)f2bf(rx) | ((unsigned)f2bf(ry) << 16);
  *(unsigned*)(voutB + (long)node * 512 + lane * 4) = ow;
  if (vout8) {
    const unsigned short o8 =
        (unsigned short)(f2fp8(rx) | (f2fp8(ry) << 8));
    *(unsigned short*)(vout8 + (long)node * 128 + lb2) = o8;
  }
}

// ---------------- dense stage (best: prefetch c_prev, depth-4 B ring) ----------------
__global__ __launch_bounds__(512, 4) void k_gemm(
    const char* __restrict__ outB, const unsigned short* __restrict__ bglob,
    const float* __restrict__ c_prev,
    const float* __restrict__ b_i, const float* __restrict__ b_f,
    const float* __restrict__ b_c, const float* __restrict__ b_o,
    const float* __restrict__ w_ci, const float* __restrict__ w_cf,
    const float* __restrict__ w_co, float* __restrict__ h_out,
    float* __restrict__ c_out) {
  __shared__ char lds[65536];
  const int tid = threadIdx.x;
  const int lane = tid & 63;
  const int w = tid >> 6;       // wave 0..7 -> hc band
  const int kg = lane >> 4;
  const int lm = lane & 15;
  const int m0 = blockIdx.x * 64;

  const char* hB = outB;                   // +0: M1 (tx1b), +256: hb
  const char* cB = outB + (long)NN * 512;  // +0: M2 (tx2b), +256: xb

  // prologue: stage the whole A panel (16 k-tiles x 4KB), 8 gload_lds/thread
  {
    const int t8 = tid & 255;
    const int rf = t8 >> 6, ln = t8 & 63;
    const int srow0 = m0 + rf * 16 + (ln & 15);
    const long srow = (srow0 < NN) ? srow0 : (NN - 1);
    const int schunk = (ln >> 4) * 16;
#pragma unroll
    for (int i = 0; i < 8; ++i) {
      const int ks = i * 2 + (tid >> 8);
      const char* base = (ks < 4) ? (cB + 256) : (ks < 8) ? (hB + 256) : (ks < 12) ? hB : cB;
      async_copy16(base + srow * 512 + (ks & 3) * 64 + schunk,
                   &lds[ks * 4096 + t8 * 16]);
    }
  }

  f32x4 acc[16];  // acc[rf*4 + g]
#pragma unroll
  for (int i = 0; i < 16; ++i) acc[i] = (f32x4){0.f, 0.f, 0.f, 0.f};

  bf16x8 B[4][4];
  auto loadB = [&](int ks, bf16x8* bb) {
    const unsigned short* fp = bglob + ((ks * 32 + w * 4) * 64 + lane) * 8;
#pragma unroll
    for (int g = 0; g < 4; ++g) bb[g] = *(const bf16x8*)(fp + g * 512);
  };

  loadB(0, B[0]);
  loadB(1, B[1]);
  loadB(2, B[2]);

  __syncthreads();  // A panel resident after this; LDS is read-only below

  const int hc = w * 16 + lm;
  float cp[16];
#pragma unroll
  for (int rf = 0; rf < 4; ++rf)
#pragma unroll
    for (int reg = 0; reg < 4; ++reg) {
      int node = m0 + rf * 16 + kg * 4 + reg;
      if (node >= NN) node = NN - 1;
      cp[rf * 4 + reg] = c_prev[node * 128 + hc];
    }
  loadB(3, B[3]);

#pragma unroll
  for (int ks = 0; ks < 16; ++ks) {
    const int m = ks & 3;
    bf16x8 a[4];
#pragma unroll
    for (int rf = 0; rf < 4; ++rf)
      a[rf] = *(const bf16x8*)(&lds[ks * 4096 + rf * 1024 + lane * 16]);
#pragma unroll
    for (int rf = 0; rf < 4; ++rf)
#pragma unroll
      for (int g = 0; g < 4; ++g)
        acc[rf * 4 + g] =
            __builtin_amdgcn_mfma_f32_16x16x32_bf16(a[rf], B[m][g], acc[rf * 4 + g], 0, 0, 0);
    if (ks + 4 < 16) loadB(ks + 4, B[m]);
  }

  const float bi = b_i[hc], bfv = b_f[hc], bc_ = b_c[hc], bo = b_o[hc];
  const float wci = w_ci[hc], wcf = w_cf[hc], wco = w_co[hc];
#pragma unroll
  for (int rf = 0; rf < 4; ++rf) {
#pragma unroll
    for (int reg = 0; reg < 4; ++reg) {
      const int node = m0 + rf * 16 + kg * 4 + reg;
      if (node < NN) {
        const float cpv = cp[rf * 4 + reg];
        const float pi = acc[rf * 4 + 0][reg] + bi + wci * cpv;
        const float pf = acc[rf * 4 + 1][reg] + bfv + wcf * cpv;
        const float pc = acc[rf * 4 + 2][reg] + bc_;
        const float po = acc[rf * 4 + 3][reg] + bo;
        const float ig = fast_sig(pi);
        const float fg = fast_sig(pf);
        const float ct = fg * cpv + ig * fast_tanh(pc);
        const float og = fast_sig(po + wco * ct);
        h_out[node * 128 + hc] = og * fast_tanh(ct);
        c_out[node * 128 + hc] = ct;
      }
    }
  }
}

// ---------------- launcher ----------------

extern "C" void kernel_launch(void* const* d_in, const int* in_sizes, int n_in,
                              void* d_out, int out_size, void* d_ws, size_t ws_size,
                              hipStream_t stream) {
  const float* x_t    = (const float*)d_in[0];
  const float* h_prev = (const float*)d_in[1];
  const float* c_prev = (const float*)d_in[2];
  const float* ew     = (const float*)d_in[3];
  const int*   eidx   = (const int*)d_in[4];
  const float* Wi = (const float*)d_in[5];
  const float* Wf = (const float*)d_in[6];
  const float* Wc = (const float*)d_in[7];
  const float* Wo = (const float*)d_in[8];
  const float* Ti = (const float*)d_in[9];
  const float* Tf = (const float*)d_in[10];
  const float* Tc = (const float*)d_in[11];
  const float* To = (const float*)d_in[12];
  const float* bi = (const float*)d_in[13];
  const float* bf = (const float*)d_in[14];
  const float* bc = (const float*)d_in[15];
  const float* bo = (const float*)d_in[16];
  const float* wci = (const float*)d_in[17];
  const float* wcf = (const float*)d_in[18];
  const float* wco = (const float*)d_in[19];

  char* ws = (char*)d_ws;
  float*    dinv  = (float*)(ws + 0);           // 200192
  int*      wscnt = (int*)(ws + 200192);        // 200192
  int*      off   = (int*)(ws + 400384);        // 200704
  int*      bsum  = (int*)(ws + 601088);        // 1024
  unsigned* ed    = (unsigned*)(ws + 602112);   // 3200000
  unsigned short* bglob = (unsigned short*)(ws + 3802112);  // 524288 -> 4326400
  unsigned char*  h8    = (unsigned char*)(ws + 4326400);   // 6400000 -> 10726400
  unsigned char*  m18   = (unsigned char*)(ws + 10726400);  // 6400000 -> 17126400

  char* outB = (char*)d_out;  // h-rows: [deg/cnt -> M1 | hb]; c-rows: [segbase/rank -> M2 | xb]
  float* h_out = (float*)d_out;
  float* c_out = h_out + (long)NN * 128;

  const int* esrc = eidx;
  const int* edst = eidx + EE;

  k_pre<<<KC + 32 + 782 + 782, 1024, 0, stream>>>(
      Wi, Wf, Wc, Wo, Ti, Tf, Tc, To, bglob, h_prev, x_t, outB, esrc, edst, ew, h8);
  k_phase2<<<12500, 256, 0, stream>>>(outB, dinv, wscnt);
  k_scan1<<<196, 256, 0, stream>>>(wscnt, bsum);
  k_scan3<<<196, 256, 0, stream>>>(wscnt, bsum, off);
  k_edge2<<<3125, 256, 0, stream>>>(esrc, edst, ew, dinv, off, outB, ed);
  k_gather<<<12500, 256, 0, stream>>>(h8, off, ed, outB, m18);               // M1 = L*h
  k_gather<<<12500, 256, 0, stream>>>(m18, off, ed, outB + (long)NN * 512,
                                      nullptr);                              // M2 = L*M1
  k_gemm<<<NPANEL, 512, 0, stream>>>(outB, bglob, c_prev,
                                     bi, bf, bc, bo, wci, wcf, wco, h_out, c_out);
}

// Round 20
// 186.316 us; speedup vs baseline: 1.0946x; 1.0946x over previous
//
#include <hip/hip_runtime.h>

#define NN 50000
#define EE 800000
#define KC 64          // histogram copies (one hist block each)
#define EPC (EE / KC)  // 12500 edges per hist block
#define DEG_SCALE 4096.0f
#define NPANEL 782

typedef float f32x4 __attribute__((ext_vector_type(4)));
typedef short bf16x8 __attribute__((ext_vector_type(8)));
typedef unsigned short u16x8 __attribute__((ext_vector_type(8)));

__device__ __forceinline__ unsigned short f2bf(float f) {
  unsigned int u = __float_as_uint(f);
  u += 0x7fffu + ((u >> 16) & 1u);
  return (unsigned short)(u >> 16);
}
__device__ __forceinline__ float bf2f(unsigned short u) {
  return __uint_as_float(((unsigned int)u) << 16);
}

__device__ __forceinline__ void async_copy16(const void* g, void* l) {
  __builtin_amdgcn_global_load_lds(
      (const __attribute__((address_space(1))) unsigned int*)g,
      (__attribute__((address_space(3))) unsigned int*)l, 16, 0, 0);
}

__device__ __forceinline__ float fast_sig(float x) {
  return __builtin_amdgcn_rcpf(1.f + __expf(-x));
}
__device__ __forceinline__ float fast_tanh(float x) {
  return 1.f - 2.f * __builtin_amdgcn_rcpf(__expf(2.f * x) + 1.f);
}

// ---- u16-slot scratch in the first 256B of each 512B d_out row ----
__device__ __forceinline__ unsigned short* hslot2(char* o, long j) {
  return (unsigned short*)(o + (j >> 7) * 512 + (j & 127) * 2);
}
// h-region slots: deg copies [0, 3.2M) ; cnt copies [3.2M, 6.4M)
// c-region slots: segbase [0, 3.2M) ; rank [3.2M, 4.0M)
#define CNT_SLOT0 3200000L
#define RANK_SLOT0 3200000L

// ---------------- phase 1: single-pass LDS histograms + buildB + h/x->bf16 ----------------
// buildB theta-fold: out = x*W + h*(th0-th2) + M1*th1 + M2*(2*th2), M2 = L*M1
__global__ __launch_bounds__(1024) void k_pre(
    const float* __restrict__ Wi, const float* __restrict__ Wf,
    const float* __restrict__ Wc, const float* __restrict__ Wo,
    const float* __restrict__ Ti, const float* __restrict__ Tf,
    const float* __restrict__ Tc, const float* __restrict__ To,
    unsigned short* __restrict__ bglob, const float* __restrict__ h,
    const float* __restrict__ x, char* __restrict__ outB,
    const int* __restrict__ src, const int* __restrict__ dst,
    const float* __restrict__ w) {
  const int b = blockIdx.x, tid = threadIdx.x;
  char* cB = outB + (long)NN * 512;
  if (b < KC) {
    __shared__ unsigned histC[12500];  //  50 KB: cnt, packed 4 x u8
    __shared__ unsigned histD[25000];  // 100 KB: deg, packed 2 x u16 fixed-point
    const int base = b * EPC;
    for (int j = tid; j < 12500; j += 1024) histC[j] = 0u;
    for (int j = tid; j < 25000; j += 1024) histD[j] = 0u;
    __syncthreads();
    for (int k = tid; k < EPC; k += 1024) {
      const int e = base + k;
      const int d = dst[e], s = src[e];
      const float wv = w[e];
      const int shc = (d & 3) * 8;
      const unsigned old = atomicAdd(&histC[d >> 2], 1u << shc);
      *hslot2(cB, RANK_SLOT0 + e) = (unsigned short)((old >> shc) & 0xffu);
      const unsigned q = (unsigned)__float2uint_rn(wv * DEG_SCALE);
      atomicAdd(&histD[s >> 1], q << ((s & 1) * 16));
    }
    __syncthreads();
    for (int j = tid; j < 12500; j += 1024) {
      const unsigned v = histC[j];
      const unsigned lo = (v & 0xffu) | (((v >> 8) & 0xffu) << 16);
      const unsigned hi = ((v >> 16) & 0xffu) | (((v >> 24) & 0xffu) << 16);
      uint2 pk; pk.x = lo; pk.y = hi;
      *(uint2*)hslot2(outB, CNT_SLOT0 + (long)b * NN + 4L * j) = pk;
    }
    for (int j = tid; j < 25000; j += 1024)
      *(unsigned*)hslot2(outB, (long)b * NN + 2L * j) = histD[j];
  } else if (b < KC + 32) {
    // buildB: fragment-native, theta-folded
    const int t = (b - KC) * 1024 + tid;  // 0..32767
    const int ks = t >> 11;
    const int cf = (t >> 6) & 31;
    const int lane = t & 63;
    const int wv = cf >> 3, hl = (cf >> 2) & 1, g = cf & 3;
    const int kg = lane >> 4, lm = lane & 15;
    const int hc = (wv * 2 + hl) * 16 + lm;
    const float* Wg = (g == 0) ? Wi : (g == 1) ? Wf : (g == 2) ? Wc : Wo;
    const float* Tg = (g == 0) ? Ti : (g == 1) ? Tf : (g == 2) ? Tc : To;
    u16x8 out;
#pragma unroll
    for (int dk = 0; dk < 8; ++dk) {
      const int k = ks * 32 + kg * 8 + dk;
      const int kb = k >> 7, r = k & 127;
      float v;
      if (kb == 0)      v = Wg[r * 128 + hc];
      else if (kb == 1) v = Tg[r * 128 + hc] - Tg[2 * 16384 + r * 128 + hc];
      else if (kb == 2) v = Tg[16384 + r * 128 + hc];
      else              v = 2.f * Tg[2 * 16384 + r * 128 + hc];
      out[dk] = f2bf(v);
    }
    *(u16x8*)(bglob + t * 8) = out;
  } else if (b < KC + 32 + 782) {
    const int i = (b - (KC + 32)) * 1024 + tid;  // 8-f32 chunks of h
    if (i < 100000 * 8) {
      const float* hp = h + i * 8;
      const f32x4 v0 = *(const f32x4*)hp;
      const f32x4 v1 = *(const f32x4*)(hp + 4);
      u16x8 o;
#pragma unroll
      for (int e = 0; e < 4; ++e) o[e] = f2bf(v0[e]);
#pragma unroll
      for (int e = 0; e < 4; ++e) o[e + 4] = f2bf(v1[e]);
      *(u16x8*)(outB + (i >> 4) * 512 + 256 + (i & 15) * 16) = o;
    }
  } else {
    const int i = (b - (KC + 32 + 782)) * 1024 + tid;
    if (i < 100000 * 8) {
      const float* xp = x + i * 8;
      const f32x4 v0 = *(const f32x4*)xp;
      const f32x4 v1 = *(const f32x4*)(xp + 4);
      u16x8 o;
#pragma unroll
      for (int e = 0; e < 4; ++e) o[e] = f2bf(v0[e]);
#pragma unroll
      for (int e = 0; e < 4; ++e) o[e + 4] = f2bf(v1[e]);
      *(u16x8*)(cB + (i >> 4) * 512 + 256 + (i & 15) * 16) = o;
    }
  }
}

// ---------------- phase 2: wave-per-node copy reduction/scan ----------------
__global__ __launch_bounds__(256) void k_phase2(char* __restrict__ outB,
                                                float* __restrict__ dinv,
                                                int* __restrict__ wscnt) {
  char* cB = outB + (long)NN * 512;
  const int lane = threadIdx.x & 63;  // copy index c
  const int i = blockIdx.x * 4 + (threadIdx.x >> 6);
  const int c = lane;
  const int cnt_c = (int)*hslot2(outB, CNT_SLOT0 + (long)c * NN + i);
  const float deg_c = (float)*hslot2(outB, (long)c * NN + i);
  int x = cnt_c;
#pragma unroll
  for (int d = 1; d < 64; d <<= 1) {
    const int y = __shfl_up(x, d, 64);
    if (lane >= d) x += y;
  }
  *hslot2(cB, (long)c * NN + i) = (unsigned short)(x - cnt_c);
  float s = deg_c;
#pragma unroll
  for (int d = 1; d < 64; d <<= 1) s += __shfl_xor(s, d, 64);
  if (lane == 0) {
    s *= (1.0f / DEG_SCALE);
    dinv[i] = (s > 0.f) ? rsqrtf(fmaxf(s, 1e-30f)) : 0.f;
  }
  if (lane == 63) wscnt[i] = x;  // inclusive node total
}

// ---------------- scan machinery ----------------
__device__ __forceinline__ int block_scan_excl_256(int v, int* total) {
  __shared__ int wsum[4];
  const int tid = threadIdx.x;
  const int lane = tid & 63, wv = tid >> 6;
  int x = v;
#pragma unroll
  for (int d = 1; d < 64; d <<= 1) {
    const int y = __shfl_up(x, d, 64);
    if (lane >= d) x += y;
  }
  if (lane == 63) wsum[wv] = x;
  __syncthreads();
  int pre = 0, tot = 0;
#pragma unroll
  for (int u = 0; u < 4; ++u) {
    const int s = wsum[u];
    pre += (u < wv) ? s : 0;
    tot += s;
  }
  *total = tot;
  return pre + x - v;
}

__global__ void k_scan1(const int* __restrict__ wscnt, int* __restrict__ bsum) {
  const int i = blockIdx.x * 256 + threadIdx.x;
  const int v = (i < NN) ? wscnt[i] : 0;
  int tot;
  block_scan_excl_256(v, &tot);
  if (threadIdx.x == 0) bsum[blockIdx.x] = tot;
}

// scan3 with self-computed block prefix
__global__ void k_scan3(const int* __restrict__ wscnt, const int* __restrict__ bsum,
                        int* __restrict__ off) {
  const int tid = threadIdx.x;
  const int vb = (tid < 196 && tid < (int)blockIdx.x) ? bsum[tid] : 0;
  int pre;
  block_scan_excl_256(vb, &pre);
  __syncthreads();
  const int i = blockIdx.x * 256 + tid;
  const int v = (i < NN) ? wscnt[i] : 0;
  int tot;
  const int excl = block_scan_excl_256(v, &tot) + pre;
  if (i < NN) off[i] = excl;
  if (i == NN) off[NN] = excl;
}

// atomic-free CSR fill: p = off[d] + segbase[copy][d] + rank[e]
// record: low16 = src (u16), high16 = wn (bf16)
__global__ void k_edge2(const int* __restrict__ src, const int* __restrict__ dst,
                        const float* __restrict__ w, const float* __restrict__ dinv,
                        const int* __restrict__ off, char* __restrict__ outB,
                        unsigned* __restrict__ ed) {
  const int e = blockIdx.x * blockDim.x + threadIdx.x;
  if (e >= EE) return;
  char* cB = outB + (long)NN * 512;
  const int s = src[e], d = dst[e];
  const int c = e / EPC;
  const int p = off[d] + (int)*hslot2(cB, (long)c * NN + d) +
                (int)*hslot2(cB, RANK_SLOT0 + e);
  const float wn = -w[e] * dinv[s] * dinv[d];
  ed[p] = (unsigned)s | ((unsigned)f2bf(wn) << 16);
}

// ---------------- sparse gather (bf16 rows, 1 wave per node, plain L*v) ----------------
__global__ __launch_bounds__(256) void k_gather(
    const char* __restrict__ vinB, const int* __restrict__ off,
    const unsigned* __restrict__ ed, char* __restrict__ voutB) {
  const int wid = threadIdx.x >> 6, lane = threadIdx.x & 63;
  const int node = blockIdx.x * 4 + wid;
  const int p0 = off[node], p1 = off[node + 1];
  const int lb = lane * 4;
  float ax0 = 0.f, ay0 = 0.f, ax1 = 0.f, ay1 = 0.f;
  float ax2 = 0.f, ay2 = 0.f, ax3 = 0.f, ay3 = 0.f;
  int p = p0;
  for (; p + 7 < p1; p += 8) {
    unsigned E[8];
    unsigned V[8];
#pragma unroll
    for (int u = 0; u < 8; ++u) E[u] = ed[p + u];
#pragma unroll
    for (int u = 0; u < 8; ++u)
      V[u] = *(const unsigned*)(vinB + (long)(E[u] & 0xffffu) * 512 + lb);
#pragma unroll
    for (int u = 0; u < 8; ++u) {
      const float wv = bf2f((unsigned short)(E[u] >> 16));
      float* ax = (u & 3) == 0 ? &ax0 : (u & 3) == 1 ? &ax1 : (u & 3) == 2 ? &ax2 : &ax3;
      float* ay = (u & 3) == 0 ? &ay0 : (u & 3) == 1 ? &ay1 : (u & 3) == 2 ? &ay2 : &ay3;
      *ax = fmaf(wv, bf2f((unsigned short)V[u]), *ax);
      *ay = fmaf(wv, bf2f((unsigned short)(V[u] >> 16)), *ay);
    }
  }
  for (; p + 3 < p1; p += 4) {
    const unsigned e0 = ed[p], e1 = ed[p + 1], e2 = ed[p + 2], e3 = ed[p + 3];
    const unsigned v0 = *(const unsigned*)(vinB + (long)(e0 & 0xffffu) * 512 + lb);
    const unsigned v1 = *(const unsigned*)(vinB + (long)(e1 & 0xffffu) * 512 + lb);
    const unsigned v2 = *(const unsigned*)(vinB + (long)(e2 & 0xffffu) * 512 + lb);
    const unsigned v3 = *(const unsigned*)(vinB + (long)(e3 & 0xffffu) * 512 + lb);
    const float w0 = bf2f((unsigned short)(e0 >> 16)), w1 = bf2f((unsigned short)(e1 >> 16));
    const float w2 = bf2f((unsigned short)(e2 >> 16)), w3 = bf2f((unsigned short)(e3 >> 16));
    ax0 = fmaf(w0, bf2f((unsigned short)v0), ax0);
    ay0 = fmaf(w0, bf2f((unsigned short)(v0 >> 16)), ay0);
    ax1 = fmaf(w1, bf2f((unsigned short)v1), ax1);
    ay1 = fmaf(w1, bf2f((unsigned short)(v1 >> 16)), ay1);
    ax2 = fmaf(w2, bf2f((unsigned short)v2), ax2);
    ay2 = fmaf(w2, bf2f((unsigned short)(v2 >> 16)), ay2);
    ax3 = fmaf(w3, bf2f((unsigned short)v3), ax3);
    ay3 = fmaf(w3, bf2f((unsigned short)(v3 >> 16)), ay3);
  }
  for (; p < p1; ++p) {
    const unsigned e0 = ed[p];
    const unsigned v0 = *(const unsigned*)(vinB + (long)(e0 & 0xffffu) * 512 + lb);
    const float w0 = bf2f((unsigned short)(e0 >> 16));
    ax0 = fmaf(w0, bf2f((unsigned short)v0), ax0);
    ay0 = fmaf(w0, bf2f((unsigned short)(v0 >> 16)), ay0);
  }
  const float rx = (ax0 + ax1) + (ax2 + ax3);
  const float ry = (ay0 + ay1) + (ay2 + ay3);
  const unsigned ow = (unsigned)f2bf(rx) | ((unsigned)f2bf(ry) << 16);
  *(unsigned*)(voutB + (long)node * 512 + lb) = ow;
}

// ---------------- dense stage (best: prefetch c_prev, depth-4 B ring) ----------------
__global__ __launch_bounds__(512, 4) void k_gemm(
    const char* __restrict__ outB, const unsigned short* __restrict__ bglob,
    const float* __restrict__ c_prev,
    const float* __restrict__ b_i, const float* __restrict__ b_f,
    const float* __restrict__ b_c, const float* __restrict__ b_o,
    const float* __restrict__ w_ci, const float* __restrict__ w_cf,
    const float* __restrict__ w_co, float* __restrict__ h_out,
    float* __restrict__ c_out) {
  __shared__ char lds[65536];
  const int tid = threadIdx.x;
  const int lane = tid & 63;
  const int w = tid >> 6;       // wave 0..7 -> hc band
  const int kg = lane >> 4;
  const int lm = lane & 15;
  const int m0 = blockIdx.x * 64;

  const char* hB = outB;                   // +0: M1 (tx1b), +256: hb
  const char* cB = outB + (long)NN * 512;  // +0: M2 (tx2b), +256: xb

  // prologue: stage the whole A panel (16 k-tiles x 4KB), 8 gload_lds/thread
  {
    const int t8 = tid & 255;
    const int rf = t8 >> 6, ln = t8 & 63;
    const int srow0 = m0 + rf * 16 + (ln & 15);
    const long srow = (srow0 < NN) ? srow0 : (NN - 1);
    const int schunk = (ln >> 4) * 16;
#pragma unroll
    for (int i = 0; i < 8; ++i) {
      const int ks = i * 2 + (tid >> 8);
      const char* base = (ks < 4) ? (cB + 256) : (ks < 8) ? (hB + 256) : (ks < 12) ? hB : cB;
      async_copy16(base + srow * 512 + (ks & 3) * 64 + schunk,
                   &lds[ks * 4096 + t8 * 16]);
    }
  }

  f32x4 acc[16];  // acc[rf*4 + g]
#pragma unroll
  for (int i = 0; i < 16; ++i) acc[i] = (f32x4){0.f, 0.f, 0.f, 0.f};

  bf16x8 B[4][4];
  auto loadB = [&](int ks, bf16x8* bb) {
    const unsigned short* fp = bglob + ((ks * 32 + w * 4) * 64 + lane) * 8;
#pragma unroll
    for (int g = 0; g < 4; ++g) bb[g] = *(const bf16x8*)(fp + g * 512);
  };

  loadB(0, B[0]);
  loadB(1, B[1]);
  loadB(2, B[2]);

  __syncthreads();  // A panel resident after this; LDS is read-only below

  const int hc = w * 16 + lm;
  float cp[16];
#pragma unroll
  for (int rf = 0; rf < 4; ++rf)
#pragma unroll
    for (int reg = 0; reg < 4; ++reg) {
      int node = m0 + rf * 16 + kg * 4 + reg;
      if (node >= NN) node = NN - 1;
      cp[rf * 4 + reg] = c_prev[node * 128 + hc];
    }
  loadB(3, B[3]);

#pragma unroll
  for (int ks = 0; ks < 16; ++ks) {
    const int m = ks & 3;
    bf16x8 a[4];
#pragma unroll
    for (int rf = 0; rf < 4; ++rf)
      a[rf] = *(const bf16x8*)(&lds[ks * 4096 + rf * 1024 + lane * 16]);
#pragma unroll
    for (int rf = 0; rf < 4; ++rf)
#pragma unroll
      for (int g = 0; g < 4; ++g)
        acc[rf * 4 + g] =
            __builtin_amdgcn_mfma_f32_16x16x32_bf16(a[rf], B[m][g], acc[rf * 4 + g], 0, 0, 0);
    if (ks + 4 < 16) loadB(ks + 4, B[m]);
  }

  const float bi = b_i[hc], bfv = b_f[hc], bc_ = b_c[hc], bo = b_o[hc];
  const float wci = w_ci[hc], wcf = w_cf[hc], wco = w_co[hc];
#pragma unroll
  for (int rf = 0; rf < 4; ++rf) {
#pragma unroll
    for (int reg = 0; reg < 4; ++reg) {
      const int node = m0 + rf * 16 + kg * 4 + reg;
      if (node < NN) {
        const float cpv = cp[rf * 4 + reg];
        const float pi = acc[rf * 4 + 0][reg] + bi + wci * cpv;
        const float pf = acc[rf * 4 + 1][reg] + bfv + wcf * cpv;
        const float pc = acc[rf * 4 + 2][reg] + bc_;
        const float po = acc[rf * 4 + 3][reg] + bo;
        const float ig = fast_sig(pi);
        const float fg = fast_sig(pf);
        const float ct = fg * cpv + ig * fast_tanh(pc);
        const float og = fast_sig(po + wco * ct);
        h_out[node * 128 + hc] = og * fast_tanh(ct);
        c_out[node * 128 + hc] = ct;
      }
    }
  }
}

// ---------------- launcher ----------------

extern "C" void kernel_launch(void* const* d_in, const int* in_sizes, int n_in,
                              void* d_out, int out_size, void* d_ws, size_t ws_size,
                              hipStream_t stream) {
  const float* x_t    = (const float*)d_in[0];
  const float* h_prev = (const float*)d_in[1];
  const float* c_prev = (const float*)d_in[2];
  const float* ew     = (const float*)d_in[3];
  const int*   eidx   = (const int*)d_in[4];
  const float* Wi = (const float*)d_in[5];
  const float* Wf = (const float*)d_in[6];
  const float* Wc = (const float*)d_in[7];
  const float* Wo = (const float*)d_in[8];
  const float* Ti = (const float*)d_in[9];
  const float* Tf = (const float*)d_in[10];
  const float* Tc = (const float*)d_in[11];
  const float* To = (const float*)d_in[12];
  const float* bi = (const float*)d_in[13];
  const float* bf = (const float*)d_in[14];
  const float* bc = (const float*)d_in[15];
  const float* bo = (const float*)d_in[16];
  const float* wci = (const float*)d_in[17];
  const float* wcf = (const float*)d_in[18];
  const float* wco = (const float*)d_in[19];

  char* ws = (char*)d_ws;
  float*    dinv  = (float*)(ws + 0);        // 200192
  int*      wscnt = (int*)(ws + 200192);     // 200192
  int*      off   = (int*)(ws + 400384);     // 200704
  int*      bsum  = (int*)(ws + 601088);     // 1024
  unsigned* ed    = (unsigned*)(ws + 602112);  // 3200000
  unsigned short* bglob = (unsigned short*)(ws + 3802112);  // 524288

  char* outB = (char*)d_out;  // h-rows: [deg/cnt -> M1 | hb]; c-rows: [segbase/rank -> M2 | xb]
  float* h_out = (float*)d_out;
  float* c_out = h_out + (long)NN * 128;

  const int* esrc = eidx;
  const int* edst = eidx + EE;

  k_pre<<<KC + 32 + 782 + 782, 1024, 0, stream>>>(
      Wi, Wf, Wc, Wo, Ti, Tf, Tc, To, bglob, h_prev, x_t, outB, esrc, edst, ew);
  k_phase2<<<12500, 256, 0, stream>>>(outB, dinv, wscnt);
  k_scan1<<<196, 256, 0, stream>>>(wscnt, bsum);
  k_scan3<<<196, 256, 0, stream>>>(wscnt, bsum, off);
  k_edge2<<<3125, 256, 0, stream>>>(esrc, edst, ew, dinv, off, outB, ed);
  k_gather<<<12500, 256, 0, stream>>>(outB + 256, off, ed, outB);            // M1 = L*h
  k_gather<<<12500, 256, 0, stream>>>(outB, off, ed, outB + (long)NN * 512); // M2 = L*M1
  k_gemm<<<NPANEL, 512, 0, stream>>>(outB, bglob, c_prev,
                                     bi, bf, bc, bo, wci, wcf, wco, h_out, c_out);
}